// Round 1
// baseline (321.803 us; speedup 1.0000x reference)
//
#include <hip/hip_runtime.h>

#define CCH 64
#define EPSV 1e-5f

typedef __attribute__((ext_vector_type(8))) short short8;
typedef __attribute__((ext_vector_type(4))) float f32x4;
typedef unsigned short ushort_t;

__device__ inline ushort_t f2bf(float f) {
    unsigned int x = __builtin_bit_cast(unsigned int, f);
    unsigned int r = (x + 0x7fffu + ((x >> 16) & 1u)) >> 16;
    return (ushort_t)r;
}

// Block-level stats reduce: each wave's lanes hold per-col partial sum/sq for
// cols (wn*32 + j*16 + lane&15). Writes one 128-float row: [0..63]=sum [64..127]=sq.
__device__ inline void block_stats(float ps0, float ps1, float pq0, float pq1,
                                   int lane, int w, float* sm, float* partial_row) {
    ps0 += __shfl_xor(ps0, 16); ps0 += __shfl_xor(ps0, 32);
    ps1 += __shfl_xor(ps1, 16); ps1 += __shfl_xor(ps1, 32);
    pq0 += __shfl_xor(pq0, 16); pq0 += __shfl_xor(pq0, 32);
    pq1 += __shfl_xor(pq1, 16); pq1 += __shfl_xor(pq1, 32);
    if (lane < 16) {
        sm[(w * 2 + 0) * 16 + lane] = ps0;
        sm[(w * 2 + 1) * 16 + lane] = ps1;
        sm[128 + (w * 2 + 0) * 16 + lane] = pq0;
        sm[128 + (w * 2 + 1) * 16 + lane] = pq1;
    }
    __syncthreads();
    int t = threadIdx.x;
    if (t < 128) {
        int c = t & 63;
        int isq = t >> 6;
        int wn = c >> 5, j = (c >> 4) & 1, ln = c & 15;
        float v = sm[isq * 128 + (wn * 2 + j) * 16 + ln]
                + sm[isq * 128 + ((wn + 2) * 2 + j) * 16 + ln];
        partial_row[isq * 64 + c] = v;
    }
}

// ---- weight prep: transpose + cvt to bf16 ----
__global__ __launch_bounds__(256) void k_prep(
    const float* __restrict__ w_fuse, const float* __restrict__ w3,
    const float* __restrict__ wup,
    ushort_t* __restrict__ wfuset, ushort_t* __restrict__ w3t, ushort_t* __restrict__ wupt) {
    int i = blockIdx.x * 256 + threadIdx.x;
    if (i < 8192) {
        int cout = i >> 7, cin = i & 127;
        wfuset[i] = f2bf(w_fuse[cin * 64 + cout]);
    } else if (i < 8192 + 110592) {
        int j = i - 8192;
        int k = j >> 12, r = j & 4095, cout = r >> 6, cin = r & 63;
        w3t[j] = f2bf(w3[k * 4096 + cin * 64 + cout]);
    } else if (i < 151552) {
        int j = i - 118784;
        int k = j >> 12, r = j & 4095, f = r >> 6, c = r & 63;
        wupt[j] = f2bf(wup[k * 4096 + c * 64 + f]);
    }
}

// ---- time embedding: emb[b][c] = silu(t[b]) @ w_temb[:,c] + b_temb[c] ----
__global__ __launch_bounds__(256) void k_emb(
    const float* __restrict__ tin, const float* __restrict__ w_temb,
    const float* __restrict__ b_temb, float* __restrict__ emb) {
    __shared__ float st[8 * 256];
    int t = threadIdx.x;
    for (int i = t; i < 2048; i += 256) { float v = tin[i]; st[i] = v / (1.f + __expf(-v)); }
    __syncthreads();
    for (int p = t; p < 512; p += 256) {
        int bb = p >> 6, c = p & 63;
        float acc = b_temb[c];
        for (int e = 0; e < 256; e++) acc += st[bb * 256 + e] * w_temb[e * 64 + c];
        emb[bb * 64 + c] = acc;
    }
}

// ---- K1: T = feats @ w_fuse (bf16 MFMA), + per-block BN1 partials ----
__global__ __launch_bounds__(256) void k_gemm_fuse(
    const float* __restrict__ feats, const ushort_t* __restrict__ wfuset,
    float* __restrict__ T, float* __restrict__ partial, int npts) {
    __shared__ ushort_t A[64 * 136];  // stride 136 shorts = 272B (16 mod 128)
    __shared__ float sm[256];
    int t = threadIdx.x, bid = blockIdx.x;
    int lane = t & 63, w = t >> 6;
    int wm = w >> 1, wn = w & 1, q = lane >> 4, ln = lane & 15;
    int nbase = bid * 64;
    // stage A (f32 -> bf16): 1024 slots of 8 floats
    for (int i = 0; i < 4; i++) {
        int slot = i * 256 + t;
        int row = slot >> 4, seg = slot & 15;
        int n = nbase + row;
        short8 val = (short8)0;
        if (n < npts) {
            const float* src = feats + (size_t)n * 128 + seg * 8;
            float4 a = *(const float4*)(src);
            float4 b = *(const float4*)(src + 4);
            ushort_t u[8] = {f2bf(a.x), f2bf(a.y), f2bf(a.z), f2bf(a.w),
                             f2bf(b.x), f2bf(b.y), f2bf(b.z), f2bf(b.w)};
            val = *(short8*)u;
        }
        *(short8*)&A[row * 136 + seg * 8] = val;
    }
    __syncthreads();
    f32x4 acc[2][2];
    for (int i = 0; i < 2; i++) for (int j = 0; j < 2; j++) acc[i][j] = (f32x4)0.f;
    for (int s = 0; s < 4; s++) {
        short8 bfr[2], afr[2];
        for (int j = 0; j < 2; j++) {
            int col = wn * 32 + j * 16 + ln;
            bfr[j] = *(const short8*)&wfuset[col * 128 + s * 32 + q * 8];
        }
        for (int i = 0; i < 2; i++) {
            int row = wm * 32 + i * 16 + ln;
            afr[i] = *(const short8*)&A[row * 136 + s * 32 + q * 8];
        }
        for (int i = 0; i < 2; i++) for (int j = 0; j < 2; j++)
            acc[i][j] = __builtin_amdgcn_mfma_f32_16x16x32_bf16(afr[i], bfr[j], acc[i][j], 0, 0, 0);
    }
    float ps[2] = {0, 0}, pq[2] = {0, 0};
    for (int i = 0; i < 2; i++) for (int j = 0; j < 2; j++) {
        int col = wn * 32 + j * 16 + ln;
        for (int r = 0; r < 4; r++) {
            float v = acc[i][j][r];
            int row = nbase + wm * 32 + i * 16 + q * 4 + r;
            if (row < npts) T[(size_t)row * 64 + col] = v;
            ps[j] += v; pq[j] += v * v;
        }
    }
    block_stats(ps[0], ps[1], pq[0], pq[1], lane, w, sm, partial + (size_t)bid * 128);
}

// ---- finalize BN: reduce partials -> scale/shift ----
__global__ __launch_bounds__(1024) void k_finalize(
    const float* __restrict__ partial, int nrows, float inv_count,
    const float* __restrict__ g, const float* __restrict__ b, float* __restrict__ prm) {
    __shared__ float sS[16 * 64], sQ[16 * 64];
    int t = threadIdx.x;
    int c = t & 63, sl = t >> 6;
    float S = 0, Q = 0;
    for (int r = sl; r < nrows; r += 16) {
        S += partial[(size_t)r * 128 + c];
        Q += partial[(size_t)r * 128 + 64 + c];
    }
    sS[sl * 64 + c] = S; sQ[sl * 64 + c] = Q;
    __syncthreads();
    if (t < 64) {
        float s = 0, qq = 0;
        for (int i = 0; i < 16; i++) { s += sS[i * 64 + t]; qq += sQ[i * 64 + t]; }
        float mean = s * inv_count;
        float var = qq * inv_count - mean * mean;
        float scale = g[t] * rsqrtf(var + EPSV);
        prm[t] = scale;
        prm[64 + t] = b[t] - mean * scale;
    }
}

// ---- apply BN1 + ReLU + emb -> h (bf16) ----
__global__ __launch_bounds__(256) void k_apply1(
    const float* __restrict__ T, const float* __restrict__ prm,
    const float* __restrict__ emb, const int* __restrict__ bidx,
    ushort_t* __restrict__ h, int npts) {
    int tid = blockIdx.x * 256 + threadIdx.x;
    if (tid >= npts * 8) return;
    int row = tid >> 3, c0 = (tid & 7) * 8;
    int bi = bidx[row];
    const float* src = T + (size_t)row * 64 + c0;
    float4 a = *(const float4*)src;
    float4 b = *(const float4*)(src + 4);
    float vals[8] = {a.x, a.y, a.z, a.w, b.x, b.y, b.z, b.w};
    ushort_t o[8];
#pragma unroll
    for (int j = 0; j < 8; j++) {
        int c = c0 + j;
        float v = prm[c] * vals[j] + prm[64 + c];
        v = fmaxf(v, 0.f) + emb[bi * 64 + c];
        o[j] = f2bf(v);
    }
    *(short8*)&h[(size_t)row * 64 + c0] = *(short8*)o;
}

// ---- apply BN2 + ReLU -> h2 (bf16) ----
__global__ __launch_bounds__(256) void k_apply2(
    const float* __restrict__ out2, const float* __restrict__ prm,
    ushort_t* __restrict__ h2, int npts) {
    int tid = blockIdx.x * 256 + threadIdx.x;
    if (tid >= npts * 8) return;
    int row = tid >> 3, c0 = (tid & 7) * 8;
    const float* src = out2 + (size_t)row * 64 + c0;
    float4 a = *(const float4*)src;
    float4 b = *(const float4*)(src + 4);
    float vals[8] = {a.x, a.y, a.z, a.w, b.x, b.y, b.z, b.w};
    ushort_t o[8];
#pragma unroll
    for (int j = 0; j < 8; j++) {
        int c = c0 + j;
        float v = prm[c] * vals[j] + prm[64 + c];
        o[j] = f2bf(fmaxf(v, 0.f));
    }
    *(short8*)&h2[(size_t)row * 64 + c0] = *(short8*)o;
}

// ---- K4: 27-offset gather-GEMM, out2 += h[nbr[k]] @ w3[k]; BN2 partials ----
__global__ __launch_bounds__(256) void k_conv27(
    const ushort_t* __restrict__ h, const ushort_t* __restrict__ w3t,
    const int* __restrict__ nbr,
    float* __restrict__ out2, float* __restrict__ partial, int npts) {
    __shared__ ushort_t A[64 * 72];  // stride 72 shorts = 144B (16 mod 128)
    __shared__ float sm[256];
    int t = threadIdx.x, bid = blockIdx.x;
    int lane = t & 63, w = t >> 6;
    int wm = w >> 1, wn = w & 1, q = lane >> 4, ln = lane & 15;
    int nbase = bid * 64;
    f32x4 acc[2][2];
    for (int i = 0; i < 2; i++) for (int j = 0; j < 2; j++) acc[i][j] = (f32x4)0.f;
    for (int k = 0; k < 27; k++) {
        // stage gathered A-tile (zeros for invalid / OOB)
        for (int i2 = 0; i2 < 2; i2++) {
            int slot = i2 * 256 + t;
            int row = slot >> 3, seg = slot & 7;
            int n = nbase + row;
            int idx = (n < npts) ? nbr[(size_t)k * npts + n] : -1;
            short8 val = (short8)0;
            if (idx >= 0) val = *(const short8*)&h[(size_t)idx * 64 + seg * 8];
            *(short8*)&A[row * 72 + seg * 8] = val;
        }
        __syncthreads();
        for (int s = 0; s < 2; s++) {
            short8 bfr[2], afr[2];
            for (int j = 0; j < 2; j++) {
                int col = wn * 32 + j * 16 + ln;
                bfr[j] = *(const short8*)&w3t[(size_t)k * 4096 + col * 64 + s * 32 + q * 8];
            }
            for (int i = 0; i < 2; i++) {
                int row = wm * 32 + i * 16 + ln;
                afr[i] = *(const short8*)&A[row * 72 + s * 32 + q * 8];
            }
            for (int i = 0; i < 2; i++) for (int j = 0; j < 2; j++)
                acc[i][j] = __builtin_amdgcn_mfma_f32_16x16x32_bf16(afr[i], bfr[j], acc[i][j], 0, 0, 0);
        }
        __syncthreads();
    }
    float ps[2] = {0, 0}, pq[2] = {0, 0};
    for (int i = 0; i < 2; i++) for (int j = 0; j < 2; j++) {
        int col = wn * 32 + j * 16 + ln;
        for (int r = 0; r < 4; r++) {
            float v = acc[i][j][r];
            int row = nbase + wm * 32 + i * 16 + q * 4 + r;
            if (row < npts) out2[(size_t)row * 64 + col] = v;
            ps[j] += v; pq[j] += v * v;
        }
    }
    block_stats(ps[0], ps[1], pq[0], pq[1], lane, w, sm, partial + (size_t)bid * 128);
}

// ---- K6/K8: up-projection. WRITE=0: stats only. WRITE=1: normalize+relu+store ----
template <int WRITE>
__global__ __launch_bounds__(256) void k_up(
    const ushort_t* __restrict__ h2, const ushort_t* __restrict__ wupt,
    const float* __restrict__ params3,
    float* __restrict__ outp, float* __restrict__ partial, int npts) {
    __shared__ ushort_t A[64 * 72];
    __shared__ float sm[256];
    int t = threadIdx.x, bid = blockIdx.x;
    int lane = t & 63, w = t >> 6;
    int wm = w >> 1, wn = w & 1, q = lane >> 4, ln = lane & 15;
    int nbase = bid * 64;
    for (int i2 = 0; i2 < 2; i2++) {
        int slot = i2 * 256 + t;
        int row = slot >> 3, seg = slot & 7;
        int n = nbase + row;
        short8 val = (short8)0;
        if (n < npts) val = *(const short8*)&h2[(size_t)n * 64 + seg * 8];
        *(short8*)&A[row * 72 + seg * 8] = val;
    }
    __syncthreads();
    float ps[2] = {0, 0}, pq[2] = {0, 0};
    float sc[2], sh[2];
    if (WRITE) {
        for (int j = 0; j < 2; j++) {
            int col = wn * 32 + j * 16 + ln;
            sc[j] = params3[col];
            sh[j] = params3[64 + col];
        }
    }
    for (int uk = 0; uk < 8; uk++) {
        f32x4 acc[2][2];
        for (int i = 0; i < 2; i++) for (int j = 0; j < 2; j++) acc[i][j] = (f32x4)0.f;
        for (int s = 0; s < 2; s++) {
            short8 bfr[2], afr[2];
            for (int j = 0; j < 2; j++) {
                int col = wn * 32 + j * 16 + ln;
                bfr[j] = *(const short8*)&wupt[(size_t)uk * 4096 + col * 64 + s * 32 + q * 8];
            }
            for (int i = 0; i < 2; i++) {
                int row = wm * 32 + i * 16 + ln;
                afr[i] = *(const short8*)&A[row * 72 + s * 32 + q * 8];
            }
            for (int i = 0; i < 2; i++) for (int j = 0; j < 2; j++)
                acc[i][j] = __builtin_amdgcn_mfma_f32_16x16x32_bf16(afr[i], bfr[j], acc[i][j], 0, 0, 0);
        }
        for (int i = 0; i < 2; i++) for (int j = 0; j < 2; j++) {
            for (int r = 0; r < 4; r++) {
                float v = acc[i][j][r];
                if (WRITE) {
                    int row = nbase + wm * 32 + i * 16 + q * 4 + r;
                    if (row < npts) {
                        float y = fmaxf(sc[j] * v + sh[j], 0.f);
                        int col = wn * 32 + j * 16 + ln;
                        outp[((size_t)row * 8 + uk) * 64 + col] = y;
                    }
                } else {
                    ps[j] += v; pq[j] += v * v;
                }
            }
        }
    }
    if (!WRITE)
        block_stats(ps[0], ps[1], pq[0], pq[1], lane, w, sm, partial + (size_t)bid * 128);
}

extern "C" void kernel_launch(void* const* d_in, const int* in_sizes, int n_in,
                              void* d_out, int out_size, void* d_ws, size_t ws_size,
                              hipStream_t stream) {
    const float* feats  = (const float*)d_in[0];
    const float* tin    = (const float*)d_in[1];
    const float* w_fuse = (const float*)d_in[2];
    const float* g1     = (const float*)d_in[3];
    const float* b1     = (const float*)d_in[4];
    const float* w_temb = (const float*)d_in[5];
    const float* b_temb = (const float*)d_in[6];
    const float* w3     = (const float*)d_in[7];
    const float* g2     = (const float*)d_in[8];
    const float* b2     = (const float*)d_in[9];
    const float* wup    = (const float*)d_in[10];
    const float* g3     = (const float*)d_in[11];
    const float* b3     = (const float*)d_in[12];
    const int* bidx     = (const int*)d_in[13];
    const int* nbr      = (const int*)d_in[14];

    int npts = in_sizes[13];  // N = 100000
    float* dout = (float*)d_out;

    // d_out doubles as scratch: T, out2, h all dead before the final full write
    float* T     = dout;
    float* out2  = dout + (size_t)npts * 64;
    ushort_t* h  = (ushort_t*)(dout + (size_t)npts * 128);

    char* ws = (char*)d_ws;
    float* partial    = (float*)ws;                           // 1563*128 f32
    float* prm        = (float*)(ws + 1048576);               // 3 x [scale64|shift64]
    float* emb        = (float*)(ws + 1048576 + 4096);        // 8 x 64
    ushort_t* wfuset  = (ushort_t*)(ws + 1048576 + 8192);
    ushort_t* w3t     = (ushort_t*)(ws + 1048576 + 8192 + 16384);
    ushort_t* wupt    = (ushort_t*)(ws + 1048576 + 8192 + 16384 + 221184);
    ushort_t* h2      = (ushort_t*)(ws + 1048576 + 8192 + 16384 + 221184 + 65536);

    int nblk = (npts + 63) / 64;  // 1563
    int napp = (npts * 8 + 255) / 256;

    k_prep<<<592, 256, 0, stream>>>(w_fuse, w3, wup, wfuset, w3t, wupt);
    k_emb<<<1, 256, 0, stream>>>(tin, w_temb, b_temb, emb);
    k_gemm_fuse<<<nblk, 256, 0, stream>>>(feats, wfuset, T, partial, npts);
    k_finalize<<<1, 1024, 0, stream>>>(partial, nblk, 1.f / npts, g1, b1, prm);
    k_apply1<<<napp, 256, 0, stream>>>(T, prm, emb, bidx, h, npts);
    k_conv27<<<nblk, 256, 0, stream>>>(h, w3t, nbr, out2, partial, npts);
    k_finalize<<<1, 1024, 0, stream>>>(partial, nblk, 1.f / npts, g2, b2, prm + 128);
    k_apply2<<<napp, 256, 0, stream>>>(out2, prm + 128, h2, npts);
    k_up<0><<<nblk, 256, 0, stream>>>(h2, wupt, prm + 256, nullptr, partial, npts);
    k_finalize<<<1, 1024, 0, stream>>>(partial, nblk, 1.f / (8.f * npts), g3, b3, prm + 256);
    k_up<1><<<nblk, 256, 0, stream>>>(h2, wupt, prm + 256, dout, nullptr, npts);
}

// Round 2
// 276.002 us; speedup vs baseline: 1.1659x; 1.1659x over previous
//
#include <hip/hip_runtime.h>

#define EPSV 1e-5f

typedef __attribute__((ext_vector_type(8))) short short8;
typedef __attribute__((ext_vector_type(4))) float f32x4;
typedef unsigned short ushort_t;

__device__ inline ushort_t f2bf(float f) {
    unsigned int x = __builtin_bit_cast(unsigned int, f);
    unsigned int r = (x + 0x7fffu + ((x >> 16) & 1u)) >> 16;
    return (ushort_t)r;
}
__device__ inline float bf2f(ushort_t u) {
    return __builtin_bit_cast(float, (unsigned int)u << 16);
}

// ---- weight prep: transpose + cvt to bf16 ----
__global__ __launch_bounds__(256) void k_prep(
    const float* __restrict__ w_fuse, const float* __restrict__ w3,
    const float* __restrict__ wup,
    ushort_t* __restrict__ wfuset, ushort_t* __restrict__ w3t, ushort_t* __restrict__ wupt) {
    int i = blockIdx.x * 256 + threadIdx.x;
    if (i < 8192) {
        int cout = i >> 7, cin = i & 127;
        wfuset[i] = f2bf(w_fuse[cin * 64 + cout]);
    } else if (i < 8192 + 110592) {
        int j = i - 8192;
        int k = j >> 12, r = j & 4095, cout = r >> 6, cin = r & 63;
        w3t[j] = f2bf(w3[k * 4096 + cin * 64 + cout]);
    } else if (i < 151552) {
        int j = i - 118784;
        int k = j >> 12, r = j & 4095, f = r >> 6, c = r & 63;
        wupt[j] = f2bf(wup[k * 4096 + c * 64 + f]);
    }
}

// ---- time embedding ----
__global__ __launch_bounds__(256) void k_emb(
    const float* __restrict__ tin, const float* __restrict__ w_temb,
    const float* __restrict__ b_temb, float* __restrict__ emb) {
    __shared__ float st[8 * 256];
    int t = threadIdx.x;
    for (int i = t; i < 2048; i += 256) { float v = tin[i]; st[i] = v / (1.f + __expf(-v)); }
    __syncthreads();
    for (int p = t; p < 512; p += 256) {
        int bb = p >> 6, c = p & 63;
        float acc = b_temb[c];
        for (int e = 0; e < 256; e++) acc += st[bb * 256 + e] * w_temb[e * 64 + c];
        emb[bb * 64 + c] = acc;
    }
}

// ---- K1: T = feats @ w_fuse, + BN1 partials. Wave w owns cols w*16+ln. ----
__global__ __launch_bounds__(256) void k_gemm_fuse(
    const float* __restrict__ feats, const ushort_t* __restrict__ wfuset,
    float* __restrict__ T, float* __restrict__ partial, int npts) {
    __shared__ ushort_t A[64 * 136];
    int t = threadIdx.x, bid = blockIdx.x;
    int lane = t & 63, w = t >> 6, q = lane >> 4, ln = lane & 15;
    int nbase = bid * 64;
    for (int i = 0; i < 4; i++) {
        int slot = i * 256 + t;
        int row = slot >> 4, seg = slot & 15;
        int n = nbase + row;
        short8 val = (short8)0;
        if (n < npts) {
            const float* src = feats + (size_t)n * 128 + seg * 8;
            float4 a = *(const float4*)(src);
            float4 b = *(const float4*)(src + 4);
            ushort_t u[8] = {f2bf(a.x), f2bf(a.y), f2bf(a.z), f2bf(a.w),
                             f2bf(b.x), f2bf(b.y), f2bf(b.z), f2bf(b.w)};
            val = *(short8*)u;
        }
        *(short8*)&A[row * 136 + seg * 8] = val;
    }
    __syncthreads();
    f32x4 acc[4];
    for (int i = 0; i < 4; i++) acc[i] = (f32x4)0.f;
    int col = w * 16 + ln;
    for (int s = 0; s < 4; s++) {
        short8 bfr = *(const short8*)&wfuset[col * 128 + s * 32 + q * 8];
        for (int i = 0; i < 4; i++) {
            short8 afr = *(const short8*)&A[(i * 16 + ln) * 136 + s * 32 + q * 8];
            acc[i] = __builtin_amdgcn_mfma_f32_16x16x32_bf16(afr, bfr, acc[i], 0, 0, 0);
        }
    }
    float ps = 0.f, pq = 0.f;
    for (int i = 0; i < 4; i++)
        for (int r = 0; r < 4; r++) {
            float v = acc[i][r];
            int row = nbase + i * 16 + q * 4 + r;
            if (row < npts) T[(size_t)row * 64 + col] = v;
            ps += v; pq += v * v;
        }
    ps += __shfl_xor(ps, 16); ps += __shfl_xor(ps, 32);
    pq += __shfl_xor(pq, 16); pq += __shfl_xor(pq, 32);
    if (lane < 16) {
        partial[(size_t)bid * 128 + col] = ps;
        partial[(size_t)bid * 128 + 64 + col] = pq;
    }
}

// ---- finalize BN ----
__global__ __launch_bounds__(1024) void k_finalize(
    const float* __restrict__ partial, int nrows, float inv_count,
    const float* __restrict__ g, const float* __restrict__ b, float* __restrict__ prm) {
    __shared__ float sS[16 * 64], sQ[16 * 64];
    int t = threadIdx.x;
    int c = t & 63, sl = t >> 6;
    float S = 0, Q = 0;
    for (int r = sl; r < nrows; r += 16) {
        S += partial[(size_t)r * 128 + c];
        Q += partial[(size_t)r * 128 + 64 + c];
    }
    sS[sl * 64 + c] = S; sQ[sl * 64 + c] = Q;
    __syncthreads();
    if (t < 64) {
        float s = 0, qq = 0;
        for (int i = 0; i < 16; i++) { s += sS[i * 64 + t]; qq += sQ[i * 64 + t]; }
        float mean = s * inv_count;
        float var = qq * inv_count - mean * mean;
        float scale = g[t] * rsqrtf(var + EPSV);
        prm[t] = scale;
        prm[64 + t] = b[t] - mean * scale;
    }
}

// ---- apply BN1 + ReLU + emb -> h (bf16) ----
__global__ __launch_bounds__(256) void k_apply1(
    const float* __restrict__ T, const float* __restrict__ prm,
    const float* __restrict__ emb, const int* __restrict__ bidx,
    ushort_t* __restrict__ h, int npts) {
    int tid = blockIdx.x * 256 + threadIdx.x;
    if (tid >= npts * 8) return;
    int row = tid >> 3, c0 = (tid & 7) * 8;
    int bi = bidx[row];
    const float* src = T + (size_t)row * 64 + c0;
    float4 a = *(const float4*)src;
    float4 b = *(const float4*)(src + 4);
    float vals[8] = {a.x, a.y, a.z, a.w, b.x, b.y, b.z, b.w};
    ushort_t o[8];
#pragma unroll
    for (int j = 0; j < 8; j++) {
        int c = c0 + j;
        float v = prm[c] * vals[j] + prm[64 + c];
        v = fmaxf(v, 0.f) + emb[bi * 64 + c];
        o[j] = f2bf(v);
    }
    *(short8*)&h[(size_t)row * 64 + c0] = *(short8*)o;
}

// ---- K4: 27-offset gather-GEMM, register-direct, no LDS/barriers ----
__global__ __launch_bounds__(256) void k_conv27(
    const ushort_t* __restrict__ h, const ushort_t* __restrict__ w3t,
    const int* __restrict__ nbr,
    ushort_t* __restrict__ out2, float* __restrict__ partial, int npts) {
    int t = threadIdx.x, bid = blockIdx.x;
    int lane = t & 63, w = t >> 6, q = lane >> 4, ln = lane & 15;
    int nbase = bid * 64;
    int col = w * 16 + ln;
    f32x4 acc[4];
    for (int i = 0; i < 4; i++) acc[i] = (f32x4)0.f;
    int rowi[4];
    bool rv[4];
    for (int i = 0; i < 4; i++) { rowi[i] = nbase + i * 16 + ln; rv[i] = rowi[i] < npts; }
    for (int k = 0; k < 27; k++) {
        const int* nb = nbr + (size_t)k * npts;
        int idx[4];
        for (int i = 0; i < 4; i++) idx[i] = rv[i] ? nb[rowi[i]] : -1;
        short8 bfr0 = *(const short8*)&w3t[(size_t)k * 4096 + col * 64 + q * 8];
        short8 bfr1 = *(const short8*)&w3t[(size_t)k * 4096 + col * 64 + 32 + q * 8];
        for (int i = 0; i < 4; i++) {
            if (__any(idx[i] >= 0)) {   // ~45% of (k,i) groups are all-invalid -> skip
                short8 a0 = (short8)0, a1 = (short8)0;
                if (idx[i] >= 0) {
                    const ushort_t* hp = h + (size_t)idx[i] * 64 + q * 8;
                    a0 = *(const short8*)hp;
                    a1 = *(const short8*)(hp + 32);
                }
                acc[i] = __builtin_amdgcn_mfma_f32_16x16x32_bf16(a0, bfr0, acc[i], 0, 0, 0);
                acc[i] = __builtin_amdgcn_mfma_f32_16x16x32_bf16(a1, bfr1, acc[i], 0, 0, 0);
            }
        }
    }
    float ps = 0.f, pq = 0.f;
    for (int i = 0; i < 4; i++)
        for (int r = 0; r < 4; r++) {
            float v = acc[i][r];
            int row = nbase + i * 16 + q * 4 + r;
            ps += v; pq += v * v;
            if (row < npts) out2[(size_t)row * 64 + col] = f2bf(v);
        }
    ps += __shfl_xor(ps, 16); ps += __shfl_xor(ps, 32);
    pq += __shfl_xor(pq, 16); pq += __shfl_xor(pq, 32);
    if (lane < 16) {
        partial[(size_t)bid * 128 + col] = ps;
        partial[(size_t)bid * 128 + 64 + col] = pq;
    }
}

// ---- apply BN2+ReLU -> h2, and fused up-projection STATS (no output write) ----
__global__ __launch_bounds__(256) void k_apply2up(
    const ushort_t* __restrict__ out2, const float* __restrict__ prm2,
    const ushort_t* __restrict__ wupt,
    ushort_t* __restrict__ h2, float* __restrict__ partial, int npts) {
    __shared__ ushort_t A[64 * 72];
    int t = threadIdx.x, bid = blockIdx.x;
    int lane = t & 63, w = t >> 6, q = lane >> 4, ln = lane & 15;
    int nbase = bid * 64;
    for (int i2 = 0; i2 < 2; i2++) {
        int slot = i2 * 256 + t;
        int row = slot >> 3, seg = slot & 7;
        int n = nbase + row;
        short8 val = (short8)0;
        if (n < npts) {
            short8 x = *(const short8*)&out2[(size_t)n * 64 + seg * 8];
            ushort_t o[8];
#pragma unroll
            for (int j = 0; j < 8; j++) {
                int c = seg * 8 + j;
                float v = prm2[c] * bf2f((ushort_t)x[j]) + prm2[64 + c];
                o[j] = f2bf(fmaxf(v, 0.f));
            }
            val = *(short8*)o;
            *(short8*)&h2[(size_t)n * 64 + seg * 8] = val;
        }
        *(short8*)&A[row * 72 + seg * 8] = val;
    }
    __syncthreads();
    int col = w * 16 + ln;
    short8 afr[4][2];
    for (int i = 0; i < 4; i++)
        for (int s = 0; s < 2; s++)
            afr[i][s] = *(const short8*)&A[(i * 16 + ln) * 72 + s * 32 + q * 8];
    float ps = 0.f, pq = 0.f;
    for (int uk = 0; uk < 8; uk++) {
        f32x4 acc[4];
        for (int i = 0; i < 4; i++) acc[i] = (f32x4)0.f;
        for (int s = 0; s < 2; s++) {
            short8 bfr = *(const short8*)&wupt[(size_t)uk * 4096 + col * 64 + s * 32 + q * 8];
            for (int i = 0; i < 4; i++)
                acc[i] = __builtin_amdgcn_mfma_f32_16x16x32_bf16(afr[i][s], bfr, acc[i], 0, 0, 0);
        }
        for (int i = 0; i < 4; i++)
            for (int r = 0; r < 4; r++) { float v = acc[i][r]; ps += v; pq += v * v; }
    }
    ps += __shfl_xor(ps, 16); ps += __shfl_xor(ps, 32);
    pq += __shfl_xor(pq, 16); pq += __shfl_xor(pq, 32);
    if (lane < 16) {
        partial[(size_t)bid * 128 + col] = ps;
        partial[(size_t)bid * 128 + 64 + col] = pq;
    }
}

// ---- final up-projection: recompute + BN3 + ReLU + store ----
__global__ __launch_bounds__(256) void k_up(
    const ushort_t* __restrict__ h2, const ushort_t* __restrict__ wupt,
    const float* __restrict__ prm3, float* __restrict__ outp, int npts) {
    int t = threadIdx.x, bid = blockIdx.x;
    int lane = t & 63, w = t >> 6, q = lane >> 4, ln = lane & 15;
    int nbase = bid * 64;
    int col = w * 16 + ln;
    short8 afr[4][2];
    for (int i = 0; i < 4; i++) {
        int row = nbase + i * 16 + ln;
        for (int s = 0; s < 2; s++)
            afr[i][s] = (row < npts) ? *(const short8*)&h2[(size_t)row * 64 + s * 32 + q * 8]
                                     : (short8)0;
    }
    float sc = prm3[col], sh = prm3[64 + col];
    for (int uk = 0; uk < 8; uk++) {
        f32x4 acc[4];
        for (int i = 0; i < 4; i++) acc[i] = (f32x4)0.f;
        for (int s = 0; s < 2; s++) {
            short8 bfr = *(const short8*)&wupt[(size_t)uk * 4096 + col * 64 + s * 32 + q * 8];
            for (int i = 0; i < 4; i++)
                acc[i] = __builtin_amdgcn_mfma_f32_16x16x32_bf16(afr[i][s], bfr, acc[i], 0, 0, 0);
        }
        for (int i = 0; i < 4; i++) {
            int row = nbase + i * 16 + q * 4;
            for (int r = 0; r < 4; r++) {
                if (row + r < npts) {
                    float y = fmaxf(sc * acc[i][r] + sh, 0.f);
                    outp[((size_t)(row + r) * 8 + uk) * 64 + col] = y;
                }
            }
        }
    }
}

extern "C" void kernel_launch(void* const* d_in, const int* in_sizes, int n_in,
                              void* d_out, int out_size, void* d_ws, size_t ws_size,
                              hipStream_t stream) {
    const float* feats  = (const float*)d_in[0];
    const float* tin    = (const float*)d_in[1];
    const float* w_fuse = (const float*)d_in[2];
    const float* g1     = (const float*)d_in[3];
    const float* b1     = (const float*)d_in[4];
    const float* w_temb = (const float*)d_in[5];
    const float* b_temb = (const float*)d_in[6];
    const float* w3     = (const float*)d_in[7];
    const float* g2     = (const float*)d_in[8];
    const float* b2     = (const float*)d_in[9];
    const float* wup    = (const float*)d_in[10];
    const float* g3     = (const float*)d_in[11];
    const float* b3     = (const float*)d_in[12];
    const int* bidx     = (const int*)d_in[13];
    const int* nbr      = (const int*)d_in[14];

    int npts = in_sizes[13];  // N = 100000
    float* dout = (float*)d_out;

    // d_out doubles as scratch (all dead before the final full write):
    char* ob = (char*)d_out;
    float* T        = (float*)ob;                                  // 25.6 MB
    ushort_t* h     = (ushort_t*)(ob + (size_t)npts * 64 * 4);     // 12.8 MB
    ushort_t* out2  = (ushort_t*)(ob + (size_t)npts * 64 * 6);     // 12.8 MB

    char* ws = (char*)d_ws;
    float* partial    = (float*)ws;                           // 1563*128 f32
    float* prm        = (float*)(ws + 1048576);               // 3 x [scale64|shift64]
    float* emb        = (float*)(ws + 1048576 + 4096);        // 8 x 64
    ushort_t* wfuset  = (ushort_t*)(ws + 1048576 + 8192);
    ushort_t* w3t     = (ushort_t*)(ws + 1048576 + 8192 + 16384);
    ushort_t* wupt    = (ushort_t*)(ws + 1048576 + 8192 + 16384 + 221184);
    ushort_t* h2      = (ushort_t*)(ws + 1048576 + 8192 + 16384 + 221184 + 65536);

    int nblk = (npts + 63) / 64;  // 1563
    int napp = (npts * 8 + 255) / 256;

    k_prep<<<592, 256, 0, stream>>>(w_fuse, w3, wup, wfuset, w3t, wupt);
    k_emb<<<1, 256, 0, stream>>>(tin, w_temb, b_temb, emb);
    k_gemm_fuse<<<nblk, 256, 0, stream>>>(feats, wfuset, T, partial, npts);
    k_finalize<<<1, 1024, 0, stream>>>(partial, nblk, 1.f / npts, g1, b1, prm);
    k_apply1<<<napp, 256, 0, stream>>>(T, prm, emb, bidx, h, npts);
    k_conv27<<<nblk, 256, 0, stream>>>(h, w3t, nbr, out2, partial, npts);
    k_finalize<<<1, 1024, 0, stream>>>(partial, nblk, 1.f / npts, g2, b2, prm + 128);
    k_apply2up<<<nblk, 256, 0, stream>>>(out2, prm + 128, wupt, h2, partial, npts);
    k_finalize<<<1, 1024, 0, stream>>>(partial, nblk, 1.f / (8.f * npts), g3, b3, prm + 256);
    k_up<<<nblk, 256, 0, stream>>>(h2, wupt, prm + 256, dout, npts);
}